// Round 1
// baseline (190.337 us; speedup 1.0000x reference)
//
#include <hip/hip_runtime.h>

typedef _Float16 half8 __attribute__((ext_vector_type(8)));
typedef float f32x4 __attribute__((ext_vector_type(4)));
typedef float float4_t __attribute__((ext_vector_type(4)));

#define DIM 512
#define S 64            // spatial side
#define NROW 4096       // S*S
#define LDSW 88         // fp16 elems per LDS row (176B stride: 16B-aligned, 2-way banks = free)

// ---------------- kernel 1: column sums of W (512x512) + bias sum ----------------
// grid 32 x 256; block b sums rows [b*16, b*16+16); wsum[0..511]=colsum, wsum[512]=sum(bias)
__global__ void colsum_kernel(const float* __restrict__ W, const float* __restrict__ bias,
                              float* __restrict__ wsum) {
    int b = blockIdx.x;
    int t = threadIdx.x;
    int c0 = t, c1 = t + 256;
    float s0 = 0.f, s1 = 0.f;
    const float* Wr = W + (size_t)b * 16 * DIM;
#pragma unroll
    for (int o = 0; o < 16; ++o) {
        s0 += Wr[o * DIM + c0];
        s1 += Wr[o * DIM + c1];
    }
    atomicAdd(&wsum[c0], s0);
    atomicAdd(&wsum[c1], s1);
    if (b == 0) {
        float bs = bias[c0] + bias[c1];
#pragma unroll
        for (int off = 32; off >= 1; off >>= 1) bs += __shfl_xor(bs, off);
        if ((t & 63) == 0) atomicAdd(&wsum[512], bs);
    }
}

// ---------------- kernel 2: per-row dots -> a = (x.wqsum + Bq)*SCALE, ks = x.wksum + Bk ----
// grid 1024 x 256 (wave per row)
__global__ void rowdot_kernel(const float* __restrict__ X,
                              const float* __restrict__ wqsum,
                              const float* __restrict__ wksum,
                              float* __restrict__ a_arr,
                              float* __restrict__ ks_arr) {
    int wave = threadIdx.x >> 6;
    int lane = threadIdx.x & 63;
    int row = blockIdx.x * 4 + wave;
    const float4_t* xr = (const float4_t*)(X + (size_t)row * DIM) + lane * 2;
    const float4_t* wq = (const float4_t*)wqsum + lane * 2;
    const float4_t* wk = (const float4_t*)wksum + lane * 2;
    float4_t x0 = xr[0], x1 = xr[1];
    float4_t q0 = wq[0], q1 = wq[1];
    float4_t k0 = wk[0], k1 = wk[1];
    float sq = 0.f, sk = 0.f;
#pragma unroll
    for (int i = 0; i < 4; i++) {
        sq += x0[i] * q0[i] + x1[i] * q1[i];
        sk += x0[i] * k0[i] + x1[i] * k1[i];
    }
#pragma unroll
    for (int off = 32; off >= 1; off >>= 1) {
        sq += __shfl_xor(sq, off);
        sk += __shfl_xor(sk, off);
    }
    if (lane == 0) {
        a_arr[row]  = (sq + wqsum[DIM]) * 0.125f;
        ks_arr[row] = sk + wksum[DIM];
    }
}

// ---------------- kernel 3: V = X @ Wv^T + bv, stored transposed as fp16 Vt[512][4096] ----
// grid 128 x 256; block mb does rows [mb*32, +32), full N=512; wave nw -> cols [nw*128,+128)
__global__ void vt_gemm_kernel(const float* __restrict__ X,
                               const float* __restrict__ Wv,
                               const float* __restrict__ bv,
                               _Float16* __restrict__ Vt) {
    int mb = blockIdx.x;
    int wv_ = threadIdx.x >> 6;
    int lane = threadIdx.x & 63;
    int lr = lane & 15;
    int lg = lane >> 4;
    int row0 = mb * 32;
    int col0 = wv_ * 128;

    f32x4 acc[2][8];
#pragma unroll
    for (int m = 0; m < 2; m++)
#pragma unroll
        for (int n = 0; n < 8; n++) acc[m][n] = (f32x4){0.f, 0.f, 0.f, 0.f};

    for (int kk = 0; kk < 16; ++kk) {
        int kbase = kk * 32 + lg * 8;
        half8 a[2];
#pragma unroll
        for (int m = 0; m < 2; m++) {
            const float4_t* p = (const float4_t*)(X + (size_t)(row0 + m * 16 + lr) * DIM + kbase);
            float4_t x0 = p[0], x1 = p[1];
            half8 h;
#pragma unroll
            for (int i = 0; i < 4; i++) { h[i] = (_Float16)x0[i]; h[i + 4] = (_Float16)x1[i]; }
            a[m] = h;
        }
#pragma unroll
        for (int n = 0; n < 8; n++) {
            const float4_t* p = (const float4_t*)(Wv + (size_t)(col0 + n * 16 + lr) * DIM + kbase);
            float4_t b0 = p[0], b1 = p[1];
            half8 hb;
#pragma unroll
            for (int i = 0; i < 4; i++) { hb[i] = (_Float16)b0[i]; hb[i + 4] = (_Float16)b1[i]; }
#pragma unroll
            for (int m = 0; m < 2; m++)
                acc[m][n] = __builtin_amdgcn_mfma_f32_16x16x32_f16(a[m], hb, acc[m][n], 0, 0, 0);
        }
    }
    // store transposed: Vt[col][row], rows contiguous per lane (reg dim)
#pragma unroll
    for (int m = 0; m < 2; m++)
#pragma unroll
        for (int n = 0; n < 8; n++) {
            int col = col0 + n * 16 + lr;
            int row = row0 + m * 16 + lg * 4;
            float bvc = bv[col];
            _Float16 tmp[4];
#pragma unroll
            for (int r = 0; r < 4; r++) tmp[r] = (_Float16)(acc[m][n][r] + bvc);
            *(uint2*)(Vt + (size_t)col * NROW + row) = *(uint2*)tmp;
        }
}

// ---------------- kernel 4: main — softmax(a*ks) then W @ V_w, write 64x512 fp32 ----------
// grid 4096 x 256 (block per (h,w))
__global__ __launch_bounds__(256) void attn_main_kernel(
        const float* __restrict__ a_arr,
        const float* __restrict__ ks_arr,
        const _Float16* __restrict__ Vt,
        float* __restrict__ out) {
    __shared__ _Float16 Wsm[64 * LDSW];
    int hw = blockIdx.x;
    int w = hw & 63;
    float a = a_arr[hw];
    int t = threadIdx.x;

    // ---- softmax phase: row p handled by 4 lanes (16 cols each) ----
    {
        int p = t >> 2, c = t & 3;
        const float4_t* kp = (const float4_t*)(ks_arr + p * 64 + c * 16);
        float4_t k0 = kp[0], k1 = kp[1], k2 = kp[2], k3 = kp[3];
        float L[16];
#pragma unroll
        for (int i = 0; i < 4; i++) {
            L[i] = a * k0[i]; L[4 + i] = a * k1[i];
            L[8 + i] = a * k2[i]; L[12 + i] = a * k3[i];
        }
        float m = L[0];
#pragma unroll
        for (int i = 1; i < 16; i++) m = fmaxf(m, L[i]);
        m = fmaxf(m, __shfl_xor(m, 1));
        m = fmaxf(m, __shfl_xor(m, 2));
        float e[16];
        float s = 0.f;
#pragma unroll
        for (int i = 0; i < 16; i++) { e[i] = __expf(L[i] - m); s += e[i]; }
        s += __shfl_xor(s, 1);
        s += __shfl_xor(s, 2);
        float r = 1.0f / s;
        half8 h0, h1;
#pragma unroll
        for (int i = 0; i < 8; i++) {
            h0[i] = (_Float16)(e[i] * r);
            h1[i] = (_Float16)(e[8 + i] * r);
        }
        *(half8*)&Wsm[p * LDSW + c * 16]     = h0;
        *(half8*)&Wsm[p * LDSW + c * 16 + 8] = h1;
    }
    __syncthreads();

    // ---- PV matmul: O[64x512] = W[64x64] @ V_w[64x512], wave nw -> cols [nw*128,+128) ----
    int wv_ = t >> 6, lane = t & 63;
    int lr = lane & 15, lg = lane >> 4;

    half8 afr[4][2];
#pragma unroll
    for (int m = 0; m < 4; m++)
#pragma unroll
        for (int ks_ = 0; ks_ < 2; ks_++)
            afr[m][ks_] = *(const half8*)&Wsm[(m * 16 + lr) * LDSW + ks_ * 32 + lg * 8];

    const _Float16* Vb = Vt + w * 64;  // + d*4096 + k
    f32x4 acc[4][8];
#pragma unroll
    for (int m = 0; m < 4; m++)
#pragma unroll
        for (int n = 0; n < 8; n++) acc[m][n] = (f32x4){0.f, 0.f, 0.f, 0.f};

#pragma unroll
    for (int n = 0; n < 8; n++) {
        int d = wv_ * 128 + n * 16 + lr;
        half8 b0 = *(const half8*)(Vb + (size_t)d * NROW + lg * 8);
        half8 b1 = *(const half8*)(Vb + (size_t)d * NROW + 32 + lg * 8);
#pragma unroll
        for (int m = 0; m < 4; m++) {
            acc[m][n] = __builtin_amdgcn_mfma_f32_16x16x32_f16(afr[m][0], b0, acc[m][n], 0, 0, 0);
            acc[m][n] = __builtin_amdgcn_mfma_f32_16x16x32_f16(afr[m][1], b1, acc[m][n], 0, 0, 0);
        }
    }

    float* outb = out + (size_t)hw * (64 * DIM);
#pragma unroll
    for (int m = 0; m < 4; m++)
#pragma unroll
        for (int n = 0; n < 8; n++) {
            int d = wv_ * 128 + n * 16 + lr;
            int p0 = m * 16 + lg * 4;
            float* op = outb + (size_t)p0 * DIM + d;
            op[0]        = acc[m][n][0];
            op[DIM]      = acc[m][n][1];
            op[2 * DIM]  = acc[m][n][2];
            op[3 * DIM]  = acc[m][n][3];
        }
}

// ---------------- launcher ----------------
extern "C" void kernel_launch(void* const* d_in, const int* in_sizes, int n_in,
                              void* d_out, int out_size, void* d_ws, size_t ws_size,
                              hipStream_t stream) {
    const float* x  = (const float*)d_in[0];
    const float* Wq = (const float*)d_in[2];
    const float* bq = (const float*)d_in[3];
    const float* Wk = (const float*)d_in[4];
    const float* bk = (const float*)d_in[5];
    const float* Wv = (const float*)d_in[6];
    const float* bv = (const float*)d_in[7];
    float* out = (float*)d_out;
    char* ws = (char*)d_ws;

    _Float16* Vt  = (_Float16*)ws;                 // 512*4096*2 = 4 MiB
    float* a_arr  = (float*)(ws + 4194304);        // 4096 f32
    float* ks_arr = (float*)(ws + 4210688);        // 4096 f32
    float* wqsum  = (float*)(ws + 4227072);        // 513 f32 (pad to 2112B)
    float* wksum  = (float*)(ws + 4229184);        // 513 f32

    hipMemsetAsync(ws + 4227072, 0, 4224, stream);
    colsum_kernel<<<32, 256, 0, stream>>>(Wq, bq, wqsum);
    colsum_kernel<<<32, 256, 0, stream>>>(Wk, bk, wksum);
    rowdot_kernel<<<1024, 256, 0, stream>>>(x, wqsum, wksum, a_arr, ks_arr);
    vt_gemm_kernel<<<128, 256, 0, stream>>>(x, Wv, bv, Vt);
    attn_main_kernel<<<4096, 256, 0, stream>>>(a_arr, ks_arr, Vt, out);
}